// Round 1
// baseline (154.758 us; speedup 1.0000x reference)
//
#include <hip/hip_runtime.h>
#include <math.h>

#define N 4096
#define D 128
#define TS 64                      // output tile per 256-thread block
#define NT (N / TS)                // 64 tile rows
#define NBLK (NT * (NT + 1) / 2)   // 2080 lower-triangle tile pairs
#define NG (N / 16)                // 256 row groups of 16

typedef __attribute__((ext_vector_type(8))) short short8;  // 8 x bf16
typedef __attribute__((ext_vector_type(4))) float f32x4;

union frag_u { short8 v; unsigned int u[4]; };

__device__ __forceinline__ unsigned int pack_bf16x2(float a, float b) {
    unsigned int ua = __float_as_uint(a), ub = __float_as_uint(b);
    ua = (ua + 0x7FFFu + ((ua >> 16) & 1u)) >> 16;
    ub = (ub + 0x7FFFu + ((ub >> 16) & 1u)) >> 16;
    return ua | (ub << 16);
}

// Kernel 1: repack O into MFMA-fragment order + compute s[i]=sqrt(1+||o_i||^2).
// Also zeroes the done-counter used by the fused last-block reduction.
__global__ __launch_bounds__(256)
void prep_kernel(const float* __restrict__ O,
                 short8* __restrict__ Ofrag,
                 float* __restrict__ s,
                 unsigned int* __restrict__ done) {
    __shared__ float psum[16][17];
    const int g    = blockIdx.x;          // 16-row group
    const int tid  = threadIdx.x;
    if (g == 0 && tid == 0) *done = 0u;   // stream-ordered before tile kernel
    const int kk   = tid >> 6;            // 0..3 (wave = K-chunk)
    const int lane = tid & 63;
    const int r16  = lane & 15;
    const int qd   = lane >> 4;           // 0..3
    const float* src = O + (size_t)(g * 16 + r16) * D + kk * 32 + qd * 8;
    const float4 v0 = *(const float4*)(src);
    const float4 v1 = *(const float4*)(src + 4);
    frag_u f;
    f.u[0] = pack_bf16x2(v0.x, v0.y);
    f.u[1] = pack_bf16x2(v0.z, v0.w);
    f.u[2] = pack_bf16x2(v1.x, v1.y);
    f.u[3] = pack_bf16x2(v1.z, v1.w);
    Ofrag[(g * 4 + kk) * 64 + lane] = f.v;
    psum[kk * 4 + qd][r16] = v0.x * v0.x + v0.y * v0.y + v0.z * v0.z + v0.w * v0.w
                           + v1.x * v1.x + v1.y * v1.y + v1.z * v1.z + v1.w * v1.w;
    __syncthreads();
    if (tid < 16) {
        float acc = 1.0f;
        #pragma unroll
        for (int x = 0; x < 16; x++) acc += psum[x][tid];
        s[g * 16 + tid] = sqrtf(acc);
    }
}

__device__ __forceinline__ float acosh_dist(float B) {
    // clamp branch |B-1|<1e-6 -> 0 (inert here: B >= ~100 for this data)
    if (fabsf(B - 1.0f) < 1e-6f) return 0.0f;
    const float Bc = fmaxf(B, 1.0f);
    return __log2f(Bc + sqrtf(fmaf(Bc, Bc, -1.0f))) * 0.6931471805599453f;
}

// Kernel 2: one 256-thread block per 64x64 lower-triangle tile; each wave a
// 16x64 strip (1x4 frags, K=128 in 4 chunks). tgt is read DIRECTLY into
// registers at C-fragment addresses (issued early, consumed post-MFMA):
// zero reuse -> LDS staging was pure overhead (barrier + 17 KB LDS).
// Final reduce is fused via last-block-done (device-scope atomics).
__global__ __launch_bounds__(256, 4)
void tile_loss_kernel(const short8* __restrict__ Fr,
                      const float* __restrict__ s,
                      const float* __restrict__ tgt,
                      float* __restrict__ partials,
                      unsigned int* __restrict__ done,
                      float* __restrict__ loss) {
    __shared__ float wsum[4];
    __shared__ int lastFlag;

    const int t = blockIdx.x;
    int ti = (int)((sqrtf(8.0f * (float)t + 1.0f) - 1.0f) * 0.5f);
    while ((ti + 1) * (ti + 2) / 2 <= t) ti++;
    while (ti * (ti + 1) / 2 > t) ti--;
    const int tj = t - ti * (ti + 1) / 2;

    const int tid  = threadIdx.x;
    const int wave = tid >> 6;                 // 0..3 -> 16-row strip
    const int lane = tid & 63;
    const int quad = lane >> 4;
    const int l16  = lane & 15;

    const int ib0 = ti * TS;
    const int jb  = tj * TS;
    const int r0  = wave * 16 + quad * 4;

    // ---- Early-issue the 16 per-lane tgt loads (64B-aligned segments).
    // C/D layout: col = l16 (+n*16), row = quad*4 + r -> addresses below.
    float tv[4][4];
    #pragma unroll
    for (int r = 0; r < 4; r++) {
        const float* trow = tgt + (size_t)(ib0 + r0 + r) * N + jb + l16;
        #pragma unroll
        for (int n = 0; n < 4; n++) tv[r][n] = trow[n * 16];
    }

    float sj[4];
    #pragma unroll
    for (int n = 0; n < 4; n++) sj[n] = s[jb + n * 16 + l16];
    float si[4];
    #pragma unroll
    for (int r = 0; r < 4; r++) si[r] = s[ib0 + r0 + r];

    // ---- MFMA: K=128 as two batches of K-chunks {0,1} and {2,3}.
    f32x4 acc[4] = {};
    const int ga4 = (ti * 4 + wave) * 4;
    const int gb4 = tj * 4 * 4;
    #pragma unroll
    for (int kp = 0; kp < 2; kp++) {
        const int k0 = kp * 2, k1 = kp * 2 + 1;
        const short8 a0 = Fr[(ga4 + k0) * 64 + lane];
        const short8 a1 = Fr[(ga4 + k1) * 64 + lane];
        short8 b0[4], b1[4];
        #pragma unroll
        for (int n = 0; n < 4; n++) {
            b0[n] = Fr[(gb4 + n * 4 + k0) * 64 + lane];
            b1[n] = Fr[(gb4 + n * 4 + k1) * 64 + lane];
        }
        #pragma unroll
        for (int n = 0; n < 4; n++)
            acc[n] = __builtin_amdgcn_mfma_f32_16x16x32_bf16(a0, b0[n], acc[n], 0, 0, 0);
        #pragma unroll
        for (int n = 0; n < 4; n++)
            acc[n] = __builtin_amdgcn_mfma_f32_16x16x32_bf16(a1, b1[n], acc[n], 0, 0, 0);
    }

    // ---- Epilogue (no barrier needed: tgt came straight to registers).
    float lsum = 0.0f;
    if (ti != tj) {
        #pragma unroll
        for (int r = 0; r < 4; r++)
            #pragma unroll
            for (int n = 0; n < 4; n++) {
                const float B = fmaf(si[r], sj[n], -acc[n][r]);
                lsum += fabsf(acosh_dist(B) - tv[r][n]);
            }
    } else {
        #pragma unroll
        for (int r = 0; r < 4; r++) {
            const int i = ib0 + r0 + r;
            #pragma unroll
            for (int n = 0; n < 4; n++) {
                const int j = jb + n * 16 + l16;
                if (j < i) {
                    const float B = fmaf(si[r], sj[n], -acc[n][r]);
                    lsum += fabsf(acosh_dist(B) - tv[r][n]);
                }
            }
        }
    }

    #pragma unroll
    for (int off = 32; off > 0; off >>= 1)
        lsum += __shfl_down(lsum, off, 64);
    if (lane == 0) wsum[wave] = lsum;
    __syncthreads();

    // ---- Fused final reduction: last block to finish sums all partials in
    // the SAME index order the old kernel 3 used -> bit-identical loss.
    if (tid == 0) {
        const float p = wsum[0] + wsum[1] + wsum[2] + wsum[3];
        // agent-scope store + acq_rel RMW: visible across XCD L2s
        __hip_atomic_store(&partials[t], p, __ATOMIC_RELAXED, __HIP_MEMORY_SCOPE_AGENT);
        const unsigned int old =
            __hip_atomic_fetch_add(done, 1u, __ATOMIC_ACQ_REL, __HIP_MEMORY_SCOPE_AGENT);
        lastFlag = (old == (unsigned int)(NBLK - 1)) ? 1 : 0;
    }
    __syncthreads();
    if (lastFlag) {
        float acc2 = 0.0f;
        for (int i = tid; i < NBLK; i += 256)
            acc2 += __hip_atomic_load(&partials[i], __ATOMIC_RELAXED, __HIP_MEMORY_SCOPE_AGENT);
        #pragma unroll
        for (int off = 32; off > 0; off >>= 1)
            acc2 += __shfl_down(acc2, off, 64);
        if (lane == 0) wsum[wave] = acc2;
        __syncthreads();
        if (tid == 0)
            loss[0] = (wsum[0] + wsum[1] + wsum[2] + wsum[3])
                    * (1.0f / ((float)N * (float)(N - 1)));
    }
}

extern "C" void kernel_launch(void* const* d_in, const int* in_sizes, int n_in,
                              void* d_out, int out_size, void* d_ws, size_t ws_size,
                              hipStream_t stream) {
    const float* O   = (const float*)d_in[0];   // [4096,128] fp32
    const float* tgt = (const float*)d_in[1];   // [4096,4096] fp32
    float* loss = (float*)d_out;                // scalar

    // ws layout: [0,1MB) frag-ordered bf16 O; then s[N]; then partials; then counter
    short8* Ofrag = (short8*)d_ws;
    float* s        = (float*)((char*)d_ws + (size_t)N * D * 2);
    float* partials = s + N;
    unsigned int* done = (unsigned int*)(partials + NBLK);

    prep_kernel<<<NG, 256, 0, stream>>>(O, Ofrag, s, done);
    tile_loss_kernel<<<NBLK, 256, 0, stream>>>(Ofrag, s, tgt, partials, done, loss);
}

// Round 2
// 119.473 us; speedup vs baseline: 1.2953x; 1.2953x over previous
//
#include <hip/hip_runtime.h>
#include <math.h>

#define N 4096
#define D 128
#define TS 64                      // output tile per 256-thread block
#define NT (N / TS)                // 64 tile rows
#define NBLK (NT * (NT + 1) / 2)   // 2080 lower-triangle tile pairs
#define NG (N / 16)                // 256 row groups of 16
#define TPAD 68                    // tgt LDS row stride (floats)

typedef __attribute__((ext_vector_type(8))) short short8;  // 8 x bf16
typedef __attribute__((ext_vector_type(4))) float f32x4;

union frag_u { short8 v; unsigned int u[4]; };

__device__ __forceinline__ unsigned int pack_bf16x2(float a, float b) {
    unsigned int ua = __float_as_uint(a), ub = __float_as_uint(b);
    ua = (ua + 0x7FFFu + ((ua >> 16) & 1u)) >> 16;
    ub = (ub + 0x7FFFu + ((ub >> 16) & 1u)) >> 16;
    return ua | (ub << 16);
}

// Kernel 1: repack O into MFMA-fragment order + compute s[i]=sqrt(1+||o_i||^2).
__global__ __launch_bounds__(256)
void prep_kernel(const float* __restrict__ O,
                 short8* __restrict__ Ofrag,
                 float* __restrict__ s) {
    __shared__ float psum[16][17];
    const int g    = blockIdx.x;          // 16-row group
    const int tid  = threadIdx.x;
    const int kk   = tid >> 6;            // 0..3 (wave = K-chunk)
    const int lane = tid & 63;
    const int r16  = lane & 15;
    const int qd   = lane >> 4;           // 0..3
    const float* src = O + (size_t)(g * 16 + r16) * D + kk * 32 + qd * 8;
    const float4 v0 = *(const float4*)(src);
    const float4 v1 = *(const float4*)(src + 4);
    frag_u f;
    f.u[0] = pack_bf16x2(v0.x, v0.y);
    f.u[1] = pack_bf16x2(v0.z, v0.w);
    f.u[2] = pack_bf16x2(v1.x, v1.y);
    f.u[3] = pack_bf16x2(v1.z, v1.w);
    Ofrag[(g * 4 + kk) * 64 + lane] = f.v;
    psum[kk * 4 + qd][r16] = v0.x * v0.x + v0.y * v0.y + v0.z * v0.z + v0.w * v0.w
                           + v1.x * v1.x + v1.y * v1.y + v1.z * v1.z + v1.w * v1.w;
    __syncthreads();
    if (tid < 16) {
        float acc = 1.0f;
        #pragma unroll
        for (int x = 0; x < 16; x++) acc += psum[x][tid];
        s[g * 16 + tid] = sqrtf(acc);
    }
}

__device__ __forceinline__ float acosh_dist(float B) {
    // clamp branch |B-1|<1e-6 -> 0 (inert here: B >= ~100 for this data)
    if (fabsf(B - 1.0f) < 1e-6f) return 0.0f;
    const float Bc = fmaxf(B, 1.0f);
    return __log2f(Bc + sqrtf(fmaf(Bc, Bc, -1.0f))) * 0.6931471805599453f;
}

// Kernel 2: one 256-thread block per 64x64 lower-triangle tile; each wave a
// 16x64 strip (1x4 frags, K=128 in 4 chunks). T14 split-staging: the 4
// coalesced float4 tgt loads are ISSUED at the top, the LDS writes happen
// AFTER the MFMA section (HBM latency hidden under frag loads + MFMA).
// __launch_bounds__(256,8): VGPR<=64 + 17.4KB LDS -> 8 blocks/CU resident
// (grid is 8.125 blocks/CU -> one fully-resident round, latency-tolerant).
__global__ __launch_bounds__(256, 8)
void tile_loss_kernel(const short8* __restrict__ Fr,
                      const float* __restrict__ s,
                      const float* __restrict__ tgt,
                      float* __restrict__ partials) {
    __shared__ float T[TS][TPAD];   // 17.4 KB
    __shared__ float wsum[4];

    const int t = blockIdx.x;
    int ti = (int)((sqrtf(8.0f * (float)t + 1.0f) - 1.0f) * 0.5f);
    while ((ti + 1) * (ti + 2) / 2 <= t) ti++;
    while (ti * (ti + 1) / 2 > t) ti--;
    const int tj = t - ti * (ti + 1) / 2;

    const int tid  = threadIdx.x;
    const int wave = tid >> 6;                 // 0..3 -> 16-row strip
    const int lane = tid & 63;
    const int quad = lane >> 4;
    const int l16  = lane & 15;

    const int ib0 = ti * TS;
    const int jb  = tj * TS;
    const int r0  = wave * 16 + quad * 4;

    // ---- Issue tgt tile loads (64x64 f32) fully coalesced, keep in regs.
    const int rr = tid >> 4;
    const int cc = (tid & 15) * 4;
    float4 tg[4];
    #pragma unroll
    for (int p = 0; p < 4; p++)
        tg[p] = *(const float4*)(tgt + (size_t)(ib0 + p * 16 + rr) * N + jb + cc);

    float sj[4];
    #pragma unroll
    for (int n = 0; n < 4; n++) sj[n] = s[jb + n * 16 + l16];
    float si[4];
    #pragma unroll
    for (int r = 0; r < 4; r++) si[r] = s[ib0 + r0 + r];

    // ---- MFMA: K=128 as two batches of K-chunks {0,1} and {2,3}.
    // a-frag (g = ti*4+wave), b-frags (g = tj*4+n): 1 KB contiguous each.
    f32x4 acc[4] = {};
    const int ga4 = (ti * 4 + wave) * 4;
    const int gb4 = tj * 4 * 4;
    #pragma unroll
    for (int kp = 0; kp < 2; kp++) {
        const int k0 = kp * 2, k1 = kp * 2 + 1;
        const short8 a0 = Fr[(ga4 + k0) * 64 + lane];
        const short8 a1 = Fr[(ga4 + k1) * 64 + lane];
        short8 b0[4], b1[4];
        #pragma unroll
        for (int n = 0; n < 4; n++) {
            b0[n] = Fr[(gb4 + n * 4 + k0) * 64 + lane];
            b1[n] = Fr[(gb4 + n * 4 + k1) * 64 + lane];
        }
        #pragma unroll
        for (int n = 0; n < 4; n++)
            acc[n] = __builtin_amdgcn_mfma_f32_16x16x32_bf16(a0, b0[n], acc[n], 0, 0, 0);
        #pragma unroll
        for (int n = 0; n < 4; n++)
            acc[n] = __builtin_amdgcn_mfma_f32_16x16x32_bf16(a1, b1[n], acc[n], 0, 0, 0);
    }

    // ---- Late LDS write of the tgt tile (redistribute to C-fragment shape).
    #pragma unroll
    for (int p = 0; p < 4; p++)
        *(float4*)&T[p * 16 + rr][cc] = tg[p];
    __syncthreads();

    // ---- Epilogue. C/D layout: col = l16, row = quad*4 + reg.
    float lsum = 0.0f;
    if (ti != tj) {
        #pragma unroll
        for (int r = 0; r < 4; r++)
            #pragma unroll
            for (int n = 0; n < 4; n++) {
                const float B  = fmaf(si[r], sj[n], -acc[n][r]);
                const float tv = T[r0 + r][n * 16 + l16];
                lsum += fabsf(acosh_dist(B) - tv);
            }
    } else {
        #pragma unroll
        for (int r = 0; r < 4; r++) {
            const int i = ib0 + r0 + r;
            #pragma unroll
            for (int n = 0; n < 4; n++) {
                const int j = jb + n * 16 + l16;
                if (j < i) {
                    const float B  = fmaf(si[r], sj[n], -acc[n][r]);
                    const float tv = T[r0 + r][n * 16 + l16];
                    lsum += fabsf(acosh_dist(B) - tv);
                }
            }
        }
    }

    #pragma unroll
    for (int off = 32; off > 0; off >>= 1)
        lsum += __shfl_down(lsum, off, 64);
    if (lane == 0) wsum[wave] = lsum;
    __syncthreads();
    if (tid == 0)
        partials[t] = wsum[0] + wsum[1] + wsum[2] + wsum[3];
}

// Kernel 3: reduce the 2080 block partials, scale, write the scalar loss.
__global__ __launch_bounds__(256)
void final_reduce_kernel(const float* __restrict__ partials,
                         float* __restrict__ loss) {
    __shared__ float wsum[4];
    const int tid  = threadIdx.x;
    const int wave = tid >> 6;
    const int lane = tid & 63;
    float acc = 0.0f;
    for (int i = tid; i < NBLK; i += 256) acc += partials[i];
    #pragma unroll
    for (int off = 32; off > 0; off >>= 1)
        acc += __shfl_down(acc, off, 64);
    if (lane == 0) wsum[wave] = acc;
    __syncthreads();
    if (tid == 0) {
        const float tot = wsum[0] + wsum[1] + wsum[2] + wsum[3];
        loss[0] = tot * (1.0f / ((float)N * (float)(N - 1)));
    }
}

extern "C" void kernel_launch(void* const* d_in, const int* in_sizes, int n_in,
                              void* d_out, int out_size, void* d_ws, size_t ws_size,
                              hipStream_t stream) {
    const float* O   = (const float*)d_in[0];   // [4096,128] fp32
    const float* tgt = (const float*)d_in[1];   // [4096,4096] fp32
    float* loss = (float*)d_out;                // scalar

    // ws layout: [0,1MB) frag-ordered bf16 O; [1MB,+16KB) s[]; then partials
    short8* Ofrag = (short8*)d_ws;
    float* s        = (float*)((char*)d_ws + (size_t)N * D * 2);
    float* partials = s + N;

    prep_kernel<<<NG, 256, 0, stream>>>(O, Ofrag, s);
    tile_loss_kernel<<<NBLK, 256, 0, stream>>>(Ofrag, s, tgt, partials);
    final_reduce_kernel<<<1, 256, 0, stream>>>(partials, loss);
}

// Round 3
// 103.304 us; speedup vs baseline: 1.4981x; 1.1565x over previous
//
#include <hip/hip_runtime.h>
#include <math.h>

#define N 4096
#define D 128
#define TS 64                      // output tile per 256-thread block
#define NT (N / TS)                // 64 tile rows
#define NBLK (NT * (NT + 1) / 2)   // 2080 lower-triangle tile pairs
#define NG (N / 16)                // 256 row groups of 16

typedef __attribute__((ext_vector_type(8))) short short8;  // 8 x bf16
typedef __attribute__((ext_vector_type(4))) float f32x4;

union frag_u { short8 v; unsigned int u[4]; };

__device__ __forceinline__ unsigned int pack_bf16x2(float a, float b) {
    unsigned int ua = __float_as_uint(a), ub = __float_as_uint(b);
    ua = (ua + 0x7FFFu + ((ua >> 16) & 1u)) >> 16;
    ub = (ub + 0x7FFFu + ((ub >> 16) & 1u)) >> 16;
    return ua | (ub << 16);
}

// Kernel 1: repack O into MFMA-fragment order + compute s[i]=sqrt(1+||o_i||^2).
__global__ __launch_bounds__(256)
void prep_kernel(const float* __restrict__ O,
                 short8* __restrict__ Ofrag,
                 float* __restrict__ s) {
    __shared__ float psum[16][17];
    const int g    = blockIdx.x;          // 16-row group
    const int tid  = threadIdx.x;
    const int kk   = tid >> 6;            // 0..3 (wave = K-chunk)
    const int lane = tid & 63;
    const int r16  = lane & 15;
    const int qd   = lane >> 4;           // 0..3
    const float* src = O + (size_t)(g * 16 + r16) * D + kk * 32 + qd * 8;
    const float4 v0 = *(const float4*)(src);
    const float4 v1 = *(const float4*)(src + 4);
    frag_u f;
    f.u[0] = pack_bf16x2(v0.x, v0.y);
    f.u[1] = pack_bf16x2(v0.z, v0.w);
    f.u[2] = pack_bf16x2(v1.x, v1.y);
    f.u[3] = pack_bf16x2(v1.z, v1.w);
    Ofrag[(g * 4 + kk) * 64 + lane] = f.v;
    psum[kk * 4 + qd][r16] = v0.x * v0.x + v0.y * v0.y + v0.z * v0.z + v0.w * v0.w
                           + v1.x * v1.x + v1.y * v1.y + v1.z * v1.z + v1.w * v1.w;
    __syncthreads();
    if (tid < 16) {
        float acc = 1.0f;
        #pragma unroll
        for (int x = 0; x < 16; x++) acc += psum[x][tid];
        s[g * 16 + tid] = sqrtf(acc);
    }
}

__device__ __forceinline__ float acosh_dist(float B) {
    // clamp branch |B-1|<1e-6 -> 0 (inert here: B >= ~100 for this data)
    if (fabsf(B - 1.0f) < 1e-6f) return 0.0f;
    const float Bc = fmaxf(B, 1.0f);
    return __log2f(Bc + sqrtf(fmaf(Bc, Bc, -1.0f))) * 0.6931471805599453f;
}

// Async 16B global->LDS (no VGPR round-trip). LDS dest must be the
// wave-uniform base; HW adds lane*16 bytes.
__device__ __forceinline__ void gload_lds16(const float* g, float* l) {
    __builtin_amdgcn_global_load_lds(
        (const __attribute__((address_space(1))) unsigned int*)g,
        (__attribute__((address_space(3))) unsigned int*)l,
        16, 0, 0);
}

// Kernel 2: one 256-thread block per 64x64 lower-triangle tile; each wave a
// 16x64 strip (1x4 frags, K=128 in 4 chunks).
// VMEM completion is IN-ORDER, so issue order is chosen deliberately:
//   1) all 20 frag loads (Ofrag: 1 MB, L2-resident, ~200-300 cy)
//   2) si/sj loads
//   3) tgt tile staging via async global_load_lds (fire-and-forget DMA,
//      completes under the MFMA phase; zero VGPRs held)
//   4) MFMA (waits only on frag regs -> vmcnt leaves staging in flight)
//   5) vmcnt(0) + barrier, epilogue reads T from LDS.
// T is linear [64][64] (global_load_lds requires contiguous dest). Epilogue
// read is a 4-way bank conflict across quads: 16 ds_read_b32 * 1.58x ~ 0.1us
// total -- accepted.
__global__ __launch_bounds__(256, 4)
void tile_loss_kernel(const short8* __restrict__ Fr,
                      const float* __restrict__ s,
                      const float* __restrict__ tgt,
                      float* __restrict__ partials) {
    __shared__ float T[TS][TS];     // 16 KB, linear
    __shared__ float wsum[4];

    const int t = blockIdx.x;
    int ti = (int)((sqrtf(8.0f * (float)t + 1.0f) - 1.0f) * 0.5f);
    while ((ti + 1) * (ti + 2) / 2 <= t) ti++;
    while (ti * (ti + 1) / 2 > t) ti--;
    const int tj = t - ti * (ti + 1) / 2;

    const int tid  = threadIdx.x;
    const int wave = tid >> 6;                 // 0..3 -> 16-row strip
    const int lane = tid & 63;
    const int quad = lane >> 4;
    const int l16  = lane & 15;

    const int ib0 = ti * TS;
    const int jb  = tj * TS;
    const int r0  = wave * 16 + quad * 4;

    // ---- 1) All frag loads up front (a: 4, b: 16; 1 KB bursts each).
    const int ga4 = (ti * 4 + wave) * 4;
    const int gb4 = tj * 4 * 4;
    short8 a[4], b[4][4];                       // 16 + 64 VGPRs
    #pragma unroll
    for (int k = 0; k < 4; k++) a[k] = Fr[(ga4 + k) * 64 + lane];
    #pragma unroll
    for (int n = 0; n < 4; n++)
        #pragma unroll
        for (int k = 0; k < 4; k++) b[n][k] = Fr[(gb4 + n * 4 + k) * 64 + lane];

    // ---- 2) s values (tiny, broadcast-friendly).
    float sj[4];
    #pragma unroll
    for (int n = 0; n < 4; n++) sj[n] = s[jb + n * 16 + l16];
    float si[4];
    #pragma unroll
    for (int r = 0; r < 4; r++) si[r] = s[ib0 + r0 + r];

    // ---- 3) Async-stage the 64x64 tgt tile. Each wave: 4 x 1 KB DMA.
    // Instruction (wave,q) covers rows [wave*16+q*4, +4); lane l supplies
    // row (+ l>>4), cols (l&15)*4 .. +3  ==> linear LDS bytes base + l*16.
    {
        const float* gsrc = tgt + (size_t)(ib0 + wave * 16 + (lane >> 4)) * N
                          + jb + (lane & 15) * 4;
        #pragma unroll
        for (int q = 0; q < 4; q++)
            gload_lds16(gsrc + (size_t)q * 4 * N, &T[wave * 16 + q * 4][0]);
    }

    // ---- 4) MFMA: K=128 in 4 chunks, 4 column-frags. Waits only on a/b.
    f32x4 acc[4] = {};
    #pragma unroll
    for (int k = 0; k < 4; k++)
        #pragma unroll
        for (int n = 0; n < 4; n++)
            acc[n] = __builtin_amdgcn_mfma_f32_16x16x32_bf16(a[k], b[n][k], acc[n], 0, 0, 0);

    // ---- 5) Drain staging DMA, then make T visible to all waves.
    asm volatile("s_waitcnt vmcnt(0)" ::: "memory");
    __syncthreads();

    // ---- Epilogue. C/D layout: col = l16, row = quad*4 + reg.
    float lsum = 0.0f;
    if (ti != tj) {
        #pragma unroll
        for (int r = 0; r < 4; r++)
            #pragma unroll
            for (int n = 0; n < 4; n++) {
                const float B  = fmaf(si[r], sj[n], -acc[n][r]);
                const float tv = T[r0 + r][n * 16 + l16];
                lsum += fabsf(acosh_dist(B) - tv);
            }
    } else {
        #pragma unroll
        for (int r = 0; r < 4; r++) {
            const int i = ib0 + r0 + r;
            #pragma unroll
            for (int n = 0; n < 4; n++) {
                const int j = jb + n * 16 + l16;
                if (j < i) {
                    const float B  = fmaf(si[r], sj[n], -acc[n][r]);
                    const float tv = T[r0 + r][n * 16 + l16];
                    lsum += fabsf(acosh_dist(B) - tv);
                }
            }
        }
    }

    #pragma unroll
    for (int off = 32; off > 0; off >>= 1)
        lsum += __shfl_down(lsum, off, 64);
    if (lane == 0) wsum[wave] = lsum;
    __syncthreads();
    if (tid == 0)
        partials[t] = wsum[0] + wsum[1] + wsum[2] + wsum[3];
}

// Kernel 3: reduce the 2080 block partials, scale, write the scalar loss.
__global__ __launch_bounds__(256)
void final_reduce_kernel(const float* __restrict__ partials,
                         float* __restrict__ loss) {
    __shared__ float wsum[4];
    const int tid  = threadIdx.x;
    const int wave = tid >> 6;
    const int lane = tid & 63;
    float acc = 0.0f;
    for (int i = tid; i < NBLK; i += 256) acc += partials[i];
    #pragma unroll
    for (int off = 32; off > 0; off >>= 1)
        acc += __shfl_down(acc, off, 64);
    if (lane == 0) wsum[wave] = acc;
    __syncthreads();
    if (tid == 0) {
        const float tot = wsum[0] + wsum[1] + wsum[2] + wsum[3];
        loss[0] = tot * (1.0f / ((float)N * (float)(N - 1)));
    }
}

extern "C" void kernel_launch(void* const* d_in, const int* in_sizes, int n_in,
                              void* d_out, int out_size, void* d_ws, size_t ws_size,
                              hipStream_t stream) {
    const float* O   = (const float*)d_in[0];   // [4096,128] fp32
    const float* tgt = (const float*)d_in[1];   // [4096,4096] fp32
    float* loss = (float*)d_out;                // scalar

    // ws layout: [0,1MB) frag-ordered bf16 O; [1MB,+16KB) s[]; then partials
    short8* Ofrag = (short8*)d_ws;
    float* s        = (float*)((char*)d_ws + (size_t)N * D * 2);
    float* partials = s + N;

    prep_kernel<<<NG, 256, 0, stream>>>(O, Ofrag, s);
    tile_loss_kernel<<<NBLK, 256, 0, stream>>>(Ofrag, s, tgt, partials);
    final_reduce_kernel<<<1, 256, 0, stream>>>(partials, loss);
}